// Round 12
// baseline (1900.285 us; speedup 1.0000x reference)
//
#include <hip/hip_runtime.h>

#define NN 2048      // points
#define NB 16        // batch
#define KK 20        // k neighbors
#define EPSF 1e-5f

typedef unsigned long long ull;
typedef _Float16 v8h __attribute__((ext_vector_type(8)));
typedef float v4f __attribute__((ext_vector_type(4)));

__device__ __forceinline__ float shflx_f(float v, int m) { return __shfl_xor(v, m, 64); }
__device__ __forceinline__ ull shflx_u64(ull v, int m) {
  int lo = __shfl_xor((int)(unsigned)v, m, 64);
  int hi = __shfl_xor((int)(unsigned)(v >> 32), m, 64);
  return (((ull)(unsigned)hi) << 32) | (unsigned)lo;
}
__device__ __forceinline__ ull packkey(float s, int n) {
  unsigned u = __float_as_uint(s);
  u = (u & 0x80000000u) ? ~u : (u | 0x80000000u);
  return (((ull)u) << 32) | (unsigned)(2047 - n);   // ties -> lowest index wins under max
}

// ---------------- prep: x[C][N] fp32 -> fragment-ready f16 hi/lo [n][Cp] + xx ----
__global__ __launch_bounds__(256) void prep_kernel(const float* __restrict__ x,
    _Float16* __restrict__ xh, _Float16* __restrict__ xl, float* __restrict__ xx,
    int C, int KB, long bstride)
{
  const int b = blockIdx.y;
  const int n = blockIdx.x * 256 + threadIdx.x;
  const float* xb = x + (size_t)b * bstride;
  const int Cp = KB * 32;
  _Float16* ph = xh + ((size_t)b * NN + n) * Cp;
  _Float16* pl = xl + ((size_t)b * NN + n) * Cp;
  float s = 0.f;
  for (int kb = 0; kb < KB; kb++) {
    for (int g = 0; g < 4; g++) {
      v8h hv, lv;
#pragma unroll
      for (int j = 0; j < 8; j++) {
        int c = kb * 32 + g * 8 + j;
        float v = (c < C) ? xb[(size_t)c * NN + n] : 0.f;
        _Float16 h = (_Float16)v;
        hv[j] = h;
        lv[j] = (_Float16)(v - (float)h);
        s = fmaf(v, v, s);
      }
      *(v8h*)(ph + kb * 32 + g * 8) = hv;
      *(v8h*)(pl + kb * 32 + g * 8) = lv;
    }
  }
  xx[b * NN + n] = s;
}

// ---------------- tile scorer: 64 queries (4 A-tiles) x 16 candidates ----------
template<int KB>
__device__ __forceinline__ void tile_scores(const v8h (&Bh)[KB], const v8h (&Bl)[KB],
    const v8h (&Ah)[4][KB], const v8h (&Al)[4][KB], float xv, v4f (&out)[4])
{
#pragma unroll
  for (int a = 0; a < 4; a++) {
    v4f a0 = {0.f, 0.f, 0.f, 0.f};
    v4f a1 = {0.f, 0.f, 0.f, 0.f};
#pragma unroll
    for (int kb = 0; kb < KB; kb++) {
      v4f& acc = (kb & 1) ? a1 : a0;
      acc = __builtin_amdgcn_mfma_f32_16x16x32_f16(Ah[a][kb], Bh[kb], acc, 0, 0, 0);
      acc = __builtin_amdgcn_mfma_f32_16x16x32_f16(Ah[a][kb], Bl[kb], acc, 0, 0, 0);
      acc = __builtin_amdgcn_mfma_f32_16x16x32_f16(Al[a][kb], Bh[kb], acc, 0, 0, 0);
    }
    v4f s = a0 + a1;
#pragma unroll
    for (int j = 0; j < 4; j++) out[a][j] = s[j] - 0.5f * xv;
  }
}

// ---------------- kNN stage 1: 512-thr blocks (8 waves, Q=64), 4 chunks of 512 -
// Same per-wave structure as the proven knn2 (64 q/wave, 2-deep ring), but 2
// waves/SIMD co-resident to hide load/chain latency. Survivor lists: chunks
// 0,1 -> slist1 (Ub); chunks 2,3 -> dead xcat tail (channels >= coff).
template<int KB>
__global__ __launch_bounds__(512, 2) void knn4(
    const _Float16* __restrict__ xh, const _Float16* __restrict__ xl,
    const float* __restrict__ xxg, ull* __restrict__ slist1,
    ull* __restrict__ sl2, int coff, int* __restrict__ cntG)
{
  __shared__ float gmL[512][33];
  __shared__ float tauL[512];
  __shared__ int scnt[512];

  const int t = threadIdx.x;
  const int lane = t & 63;
  const int wave = t >> 6;
  const int col = lane & 15;
  const int quad = lane >> 4;
  const int quad8 = quad * 8;
  const int b = blockIdx.x >> 2;
  const int chunk = blockIdx.x & 3;
  const int qg = blockIdx.y;
  const int Cp = KB * 32;
  const int cb = chunk * 512;
  const _Float16* xhb = xh + (size_t)b * NN * Cp;
  const _Float16* xlb = xl + (size_t)b * NN * Cp;
  const float* xxb = xxg + b * NN;

  v8h Ah[4][KB], Al[4][KB];
  const int qw = qg * 512 + wave * 64;
#pragma unroll
  for (int a = 0; a < 4; a++) {
    const _Float16* pa = xhb + (size_t)(qw + a * 16 + col) * Cp + quad8;
    const _Float16* pb = xlb + (size_t)(qw + a * 16 + col) * Cp + quad8;
#pragma unroll
    for (int kb = 0; kb < KB; kb++) {
      Ah[a][kb] = *(const v8h*)(pa + kb * 32);
      Al[a][kb] = *(const v8h*)(pb + kb * 32);
    }
  }

  v8h Bh[2][KB], Bl[2][KB];
  float xvb[2];
  auto loadB = [&](int slot, int tt) {
    int t2 = tt < 31 ? tt : 31;
    int n = cb + t2 * 16 + col;
    const _Float16* pb = xhb + (size_t)n * Cp + quad8;
    const _Float16* pl = xlb + (size_t)n * Cp + quad8;
#pragma unroll
    for (int kb = 0; kb < KB; kb++) {
      Bh[slot][kb] = *(const v8h*)(pb + kb * 32);
      Bl[slot][kb] = *(const v8h*)(pl + kb * 32);
    }
    xvb[slot] = xxb[n];
  };

  // ---- pass 1: group maxima (16 cols x 2 tile-parities = 32 groups/query) ----
  float gm[4][8];
#pragma unroll
  for (int a = 0; a < 4; a++)
#pragma unroll
    for (int j = 0; j < 8; j++) gm[a][j] = -3.4e38f;

  loadB(0, 0);
  for (int tt = 0; tt < 32; tt += 2) {
    loadB(1, tt + 1);
    {
      v4f out[4];
      tile_scores<KB>(Bh[0], Bl[0], Ah, Al, xvb[0], out);
#pragma unroll
      for (int a = 0; a < 4; a++)
#pragma unroll
        for (int j = 0; j < 4; j++) gm[a][j * 2] = fmaxf(gm[a][j * 2], out[a][j]);
    }
    loadB(0, tt + 2);
    {
      v4f out[4];
      tile_scores<KB>(Bh[1], Bl[1], Ah, Al, xvb[1], out);
#pragma unroll
      for (int a = 0; a < 4; a++)
#pragma unroll
        for (int j = 0; j < 4; j++) gm[a][j * 2 + 1] = fmaxf(gm[a][j * 2 + 1], out[a][j]);
    }
  }

  // wave-private LDS rows -> no barrier, just lgkm drain
#pragma unroll
  for (int a = 0; a < 4; a++)
#pragma unroll
    for (int j = 0; j < 4; j++) {
      int qi = wave * 64 + a * 16 + quad * 4 + j;
      gmL[qi][col * 2 + 0] = gm[a][j * 2 + 0];
      gmL[qi][col * 2 + 1] = gm[a][j * 2 + 1];
    }
  scnt[t] = 0;
  asm volatile("s_waitcnt lgkmcnt(0)" ::: "memory");

  // tau = rank-19 of 32 group maxima (provably <= true 20th score of the chunk)
  for (int r = 0; r < 32; r++) {
    const int q = wave * 64 + r * 2 + (lane >> 5);
    const int idx = lane & 31;
    float v = gmL[q][idx];
#pragma unroll
    for (int kk = 2; kk <= 32; kk <<= 1) {
#pragma unroll
      for (int m = kk >> 1; m >= 1; m >>= 1) {
        float o = shflx_f(v, m);
        bool keepmax = ((idx & kk) == 0) == ((idx & m) == 0);
        v = keepmax ? fmaxf(v, o) : fminf(v, o);
      }
    }
    if (idx == 19) tauL[q] = v;
  }
  asm volatile("s_waitcnt lgkmcnt(0)" ::: "memory");

  float tq[4][4];
#pragma unroll
  for (int a = 0; a < 4; a++)
#pragma unroll
    for (int j = 0; j < 4; j++) tq[a][j] = tauL[wave * 64 + a * 16 + quad * 4 + j];

  // ---- pass 2: bitwise-identical rescore, compact survivors >= tau ----
  ull* slq0 = (chunk < 2)
      ? slist1 + ((size_t)b * NN + qg * 512) * 128 + chunk * 64
      : sl2 + ((size_t)b * 512 + coff) * 1024 + (size_t)(qg * 512) * 128 + (chunk - 2) * 64;
  loadB(0, 0);
  for (int tt = 0; tt < 32; tt += 2) {
    loadB(1, tt + 1);
    for (int s = 0; s < 2; s++) {
      v4f out[4];
      tile_scores<KB>(s ? Bh[1] : Bh[0], s ? Bl[1] : Bl[0], Ah, Al, xvb[s], out);
      int n = cb + (tt + s) * 16 + col;
#pragma unroll
      for (int a = 0; a < 4; a++)
#pragma unroll
        for (int j = 0; j < 4; j++) {
          float sc = out[a][j];
          if (sc >= tq[a][j]) {
            int qi = wave * 64 + a * 16 + quad * 4 + j;
            int pos = atomicAdd(&scnt[qi], 1);
            if (pos < 64) slq0[(size_t)qi * 128 + pos] = packkey(sc, n);
          }
        }
      if (s == 0) loadB(0, tt + 2);
    }
  }
  asm volatile("s_waitcnt lgkmcnt(0)" ::: "memory");
  cntG[((size_t)b * NN + qg * 512 + t) * 4 + chunk] = scnt[t];
}

// ---------------- kNN stage 2: merge 4 chunk survivor lists -> top-20 --------
__global__ __launch_bounds__(256) void knn_merge4(const ull* __restrict__ slist1,
    const ull* __restrict__ sl2, int coff, const int* __restrict__ cntG,
    const _Float16* __restrict__ xh, const _Float16* __restrict__ xl,
    const float* __restrict__ xxg, int* __restrict__ idxout, int Cp, int C)
{
  const int lane = threadIdx.x & 63, wave = threadIdx.x >> 6;
  const int b = blockIdx.y;
  const int q = blockIdx.x * 4 + wave;
  const size_t qb = (size_t)b * NN + q;
  const int c0 = cntG[qb * 4 + 0], c1 = cntG[qb * 4 + 1];
  const int c2 = cntG[qb * 4 + 2], c3 = cntG[qb * 4 + 3];
  int* op = idxout + qb * KK;

  if (c0 <= 64 && c1 <= 64 && c2 <= 64 && c3 <= 64) {
    const ull* seg01 = slist1 + qb * 128;
    const ull* seg23 = sl2 + ((size_t)b * 512 + coff) * 1024 + (size_t)q * 128;
    const int O1 = c0, O2 = c0 + c1, O3 = c0 + c1 + c2, tot = O3 + c3;
    ull e[4];
#pragma unroll
    for (int i = 0; i < 4; i++) {
      int p = lane + i * 64;
      ull v = 0;
      if (p < tot) {
        if (p < O1)      v = seg01[p];
        else if (p < O2) v = seg01[64 + p - O1];
        else if (p < O3) v = seg23[p - O2];
        else             v = seg23[64 + p - O3];
      }
      e[i] = v;
    }
    for (int s = 0; s < KK; s++) {
      ull m = e[0] > e[1] ? e[0] : e[1];
      ull m2 = e[2] > e[3] ? e[2] : e[3];
      m = m > m2 ? m : m2;
      ull g = m;
#pragma unroll
      for (int d = 1; d < 64; d <<= 1) { ull o = shflx_u64(g, d); g = o > g ? o : g; }
      if (lane == 0) op[s] = 2047 - (int)(g & 0xFFFFFFFFu);
      if (e[0] == g) e[0] = 0;
      else if (e[1] == g) e[1] = 0;
      else if (e[2] == g) e[2] = 0;
      else if (e[3] == g) e[3] = 0;
    }
  } else {
    // exact fallback (survivor cap overflow — expected never): full fp32 rescan
    const _Float16* qh = xh + ((size_t)b * NN + q) * Cp;
    const _Float16* ql = xl + ((size_t)b * NN + q) * Cp;
    const float* xxb = xxg + b * NN;
    float sc[32];
#pragma unroll
    for (int i = 0; i < 32; i++) sc[i] = -0.5f * xxb[lane + 64 * i];
    for (int c = 0; c < C; c++) {
      float qv = (float)qh[c] + (float)ql[c];
      for (int i = 0; i < 32; i++) {
        int n = lane + 64 * i;
        float bv = (float)xh[((size_t)b * NN + n) * Cp + c] + (float)xl[((size_t)b * NN + n) * Cp + c];
        sc[i] = fmaf(qv, bv, sc[i]);
      }
    }
    for (int s = 0; s < KK; s++) {
      ull m = 0; int mi = -1;
      for (int i = 0; i < 32; i++) {
        ull k = packkey(sc[i], lane + 64 * i);
        if (k > m) { m = k; mi = i; }
      }
      ull g = m;
#pragma unroll
      for (int d = 1; d < 64; d <<= 1) { ull o = shflx_u64(g, d); g = o > g ? o : g; }
      if (lane == 0) op[s] = 2047 - (int)(g & 0xFFFFFFFFu);
      if (m == g && mi >= 0) sc[mi] = -3.4e38f;
    }
  }
}

// ---------------- weight converts ----------------
__global__ __launch_bounds__(256) void wcvt_uv(const float* __restrict__ w,
    _Float16* __restrict__ wuh, _Float16* __restrict__ wul,
    _Float16* __restrict__ wvh, _Float16* __restrict__ wvl, int C, int Cp, int O)
{
  int idx = blockIdx.x * 256 + threadIdx.x;
  if (idx >= O * Cp) return;
  int o = idx / Cp, c = idx - o * Cp;
  float a = 0.f, bv = 0.f;
  if (c < C) { a = w[o * 2 * C + c]; bv = w[o * 2 * C + C + c]; }
  float v = bv - a;
  _Float16 ah = (_Float16)a; wuh[idx] = ah; wul[idx] = (_Float16)(a - (float)ah);
  _Float16 vh = (_Float16)v; wvh[idx] = vh; wvl[idx] = (_Float16)(v - (float)vh);
}

__global__ __launch_bounds__(256) void w5cvt(const float* __restrict__ w5,
    _Float16* __restrict__ w5h, _Float16* __restrict__ w5l)
{
  int idx = blockIdx.x * 256 + threadIdx.x;
  float v = w5[idx];
  _Float16 h = (_Float16)v;
  w5h[idx] = h;
  w5l[idx] = (_Float16)(v - (float)h);
}

// ---------------- xcat fp32 [b][c][n] -> f16 hi/lo fragments [b][kc][n][32] ----
__global__ __launch_bounds__(256) void y5cvt_kernel(const float* __restrict__ xcat,
    _Float16* __restrict__ xh, _Float16* __restrict__ xl)
{
  const int b = blockIdx.y;
  const int n = blockIdx.x * 256 + threadIdx.x;
  for (int kc = blockIdx.z * 4; kc < blockIdx.z * 4 + 4; kc++) {
    v8h h[4], l[4];
#pragma unroll
    for (int g = 0; g < 4; g++)
#pragma unroll
      for (int j = 0; j < 8; j++) {
        float v = xcat[((size_t)b * 512 + kc * 32 + g * 8 + j) * NN + n];
        _Float16 hh = (_Float16)v;
        h[g][j] = hh;
        l[g][j] = (_Float16)(v - (float)hh);
      }
    size_t base = (((size_t)b * 16 + kc) * NN + n) * 32;
#pragma unroll
    for (int g = 0; g < 4; g++) {
      *(v8h*)(xh + base + g * 8) = h[g];
      *(v8h*)(xl + base + g * 8) = l[g];
    }
  }
}

// ---------------- y5 = w5 * xcat via MFMA (f16 hi/lo 3-product) ----------------
__global__ __launch_bounds__(256) void y5_mfma(const _Float16* __restrict__ w5h,
    const _Float16* __restrict__ w5l, const _Float16* __restrict__ xh,
    const _Float16* __restrict__ xl, float* __restrict__ y5)
{
  const int lane = threadIdx.x & 63, wave = threadIdx.x >> 6;
  const int col = lane & 15, quad = lane >> 4, quad8 = quad * 8;
  const int b = blockIdx.z;
  const int o0 = blockIdx.x * 256 + wave * 64;
  const int nb0 = blockIdx.y * 128;
  v4f acc[4][8];
#pragma unroll
  for (int a = 0; a < 4; a++)
#pragma unroll
    for (int t = 0; t < 8; t++) acc[a][t] = {0.f, 0.f, 0.f, 0.f};

  for (int kc = 0; kc < 16; kc++) {
    v8h Ah[4], Al[4];
#pragma unroll
    for (int a = 0; a < 4; a++) {
      size_t off = (size_t)(o0 + a * 16 + col) * 512 + kc * 32 + quad8;
      Ah[a] = *(const v8h*)(w5h + off);
      Al[a] = *(const v8h*)(w5l + off);
    }
#pragma unroll
    for (int t = 0; t < 8; t++) {
      int n = nb0 + t * 16 + col;
      size_t boff = (((size_t)b * 16 + kc) * NN + n) * 32 + quad8;
      v8h Bh = *(const v8h*)(xh + boff);
      v8h Bl = *(const v8h*)(xl + boff);
#pragma unroll
      for (int a = 0; a < 4; a++) {
        acc[a][t] = __builtin_amdgcn_mfma_f32_16x16x32_f16(Ah[a], Bh, acc[a][t], 0, 0, 0);
        acc[a][t] = __builtin_amdgcn_mfma_f32_16x16x32_f16(Ah[a], Bl, acc[a][t], 0, 0, 0);
        acc[a][t] = __builtin_amdgcn_mfma_f32_16x16x32_f16(Al[a], Bh, acc[a][t], 0, 0, 0);
      }
    }
  }
#pragma unroll
  for (int a = 0; a < 4; a++)
#pragma unroll
    for (int t = 0; t < 8; t++)
#pragma unroll
      for (int j = 0; j < 4; j++)
        y5[((size_t)b * 512 + o0 + a * 16 + quad * 4 + j) * NN + nb0 + t * 16 + col] = acc[a][t][j];
}

// ---------------- U/V chunk (up to 128 out-ch) via MFMA, 4 n-tiles/wave --------
__global__ __launch_bounds__(256) void uv_mfma(const _Float16* __restrict__ wuh,
    const _Float16* __restrict__ wul, const _Float16* __restrict__ wvh,
    const _Float16* __restrict__ wvl, const _Float16* __restrict__ xh,
    const _Float16* __restrict__ xl, float* __restrict__ Uc, float* __restrict__ Vc,
    int Cp, int Och)
{
  const int lane = threadIdx.x & 63, wave = threadIdx.x >> 6;
  const int col = lane & 15, quad = lane >> 4, quad8 = quad * 8;
  const int b = blockIdx.z;
  const int o0 = blockIdx.x * 32;           // chunk-local out channel base
  const int nb0 = blockIdx.y * 256 + wave * 64;
  v4f aU[2][4], aV[2][4];
#pragma unroll
  for (int a = 0; a < 2; a++)
#pragma unroll
    for (int t = 0; t < 4; t++) { aU[a][t] = {0.f,0.f,0.f,0.f}; aV[a][t] = {0.f,0.f,0.f,0.f}; }

  const int KBr = Cp >> 5;
  for (int kb = 0; kb < KBr; kb++) {
    v8h Uh[2], Ul[2], Vh[2], Vl[2];
#pragma unroll
    for (int a = 0; a < 2; a++) {
      size_t off = (size_t)(o0 + a * 16 + col) * Cp + kb * 32 + quad8;
      Uh[a] = *(const v8h*)(wuh + off);
      Ul[a] = *(const v8h*)(wul + off);
      Vh[a] = *(const v8h*)(wvh + off);
      Vl[a] = *(const v8h*)(wvl + off);
    }
#pragma unroll
    for (int t = 0; t < 4; t++) {
      int n = nb0 + t * 16 + col;
      size_t boff = ((size_t)b * NN + n) * Cp + kb * 32 + quad8;
      v8h Bh = *(const v8h*)(xh + boff);
      v8h Bl = *(const v8h*)(xl + boff);
#pragma unroll
      for (int a = 0; a < 2; a++) {
        aU[a][t] = __builtin_amdgcn_mfma_f32_16x16x32_f16(Uh[a], Bh, aU[a][t], 0, 0, 0);
        aU[a][t] = __builtin_amdgcn_mfma_f32_16x16x32_f16(Uh[a], Bl, aU[a][t], 0, 0, 0);
        aU[a][t] = __builtin_amdgcn_mfma_f32_16x16x32_f16(Ul[a], Bh, aU[a][t], 0, 0, 0);
        aV[a][t] = __builtin_amdgcn_mfma_f32_16x16x32_f16(Vh[a], Bh, aV[a][t], 0, 0, 0);
        aV[a][t] = __builtin_amdgcn_mfma_f32_16x16x32_f16(Vh[a], Bl, aV[a][t], 0, 0, 0);
        aV[a][t] = __builtin_amdgcn_mfma_f32_16x16x32_f16(Vl[a], Bh, aV[a][t], 0, 0, 0);
      }
    }
  }
#pragma unroll
  for (int a = 0; a < 2; a++)
#pragma unroll
    for (int t = 0; t < 4; t++)
#pragma unroll
      for (int j = 0; j < 4; j++) {
        size_t base = ((size_t)b * Och + o0 + a * 16 + quad * 4 + j) * NN + nb0 + t * 16 + col;
        Uc[base] = aU[a][t][j];
        Vc[base] = aV[a][t][j];
      }
}

// ---------------- edge5: 2 channels/block, 2-pass, 2-4 blocks/CU ---------------
__global__ __launch_bounds__(256) void edge5(const float* __restrict__ Uc,
    const float* __restrict__ Vc, const int* __restrict__ idx,
    float* __restrict__ xo, int Och)
{
  __shared__ float Ur[2 * 2052];   // +4 pad breaks power-of-2 collisions
  __shared__ float red[4][4];
  __shared__ float smv[4];
  const int b = blockIdx.y, o0 = blockIdx.x * 2;
  const int t = threadIdx.x, lane = t & 63, wave = t >> 6;
  for (int r = 0; r < 2; r++)
    for (int i = t; i < NN; i += 256)
      Ur[r * 2052 + i] = Uc[((size_t)b * Och + o0 + r) * NN + i];
  __syncthreads();
  const float* Vp = Vc + ((size_t)b * Och + o0) * NN;
  const int* ib = idx + (size_t)b * NN * KK;
  float s0 = 0, s1 = 0, c0 = 0, c1 = 0;
  for (int n = t; n < NN; n += 256) {
    float v0 = Vp[n], v1 = Vp[NN + n];
    const int* ip = ib + (size_t)n * KK;
#pragma unroll
    for (int j = 0; j < KK; j++) {
      int m = ip[j];
      float y0 = Ur[m] + v0, y1 = Ur[2052 + m] + v1;
      s0 += y0; c0 = fmaf(y0, y0, c0);
      s1 += y1; c1 = fmaf(y1, y1, c1);
    }
  }
  float st[4] = { s0, s1, c0, c1 };
#pragma unroll
  for (int k = 0; k < 4; k++) {
    float a = st[k];
#pragma unroll
    for (int d = 1; d < 64; d <<= 1) a += shflx_f(a, d);
    if (lane == 0) red[k][wave] = a;
  }
  __syncthreads();
  if (t < 2) {
    float a = red[t][0] + red[t][1] + red[t][2] + red[t][3];
    float c = red[2 + t][0] + red[2 + t][1] + red[2 + t][2] + red[2 + t][3];
    const float inv = 1.f / (float)(NN * KK);
    float mu = a * inv;
    float var = fmaxf(c * inv - mu * mu, 0.f);
    smv[t] = mu;
    smv[2 + t] = rsqrtf(var + EPSF);
  }
  __syncthreads();
  const float mu0 = smv[0], mu1 = smv[1], i0 = smv[2], i1 = smv[3];
  for (int n = t; n < NN; n += 256) {
    float v0 = Vp[n], v1 = Vp[NN + n];
    const int* ip = ib + (size_t)n * KK;
    float m0 = -3.4e38f, m1 = m0;
#pragma unroll
    for (int j = 0; j < KK; j++) {
      int m = ip[j];
      m0 = fmaxf(m0, Ur[m] + v0);
      m1 = fmaxf(m1, Ur[2052 + m] + v1);
    }
    float z;  // leaky-relu commutes with max (i > 0)
    z = (m0 - mu0) * i0; xo[((size_t)b * 512 + o0 + 0) * NN + n] = z >= 0.f ? z : 0.2f * z;
    z = (m1 - mu1) * i1; xo[((size_t)b * 512 + o0 + 1) * NN + n] = z >= 0.f ? z : 0.2f * z;
  }
}

__global__ __launch_bounds__(256) void bn5stat_kernel(const float* __restrict__ y5,
    float* __restrict__ bn5) {
  __shared__ float rs[4], rq[4];
  const int o = blockIdx.x, t = threadIdx.x, lane = t & 63, wave = t >> 6;
  float s = 0.f, q = 0.f;
  for (int b = 0; b < NB; b++) {
    const float* p = y5 + ((size_t)b * 512 + o) * NN;
    for (int n = t; n < NN; n += 256) { float v = p[n]; s += v; q = fmaf(v, v, q); }
  }
#pragma unroll
  for (int d = 1; d < 64; d <<= 1) { s += shflx_f(s, d); q += shflx_f(q, d); }
  if (lane == 0) { rs[wave] = s; rq[wave] = q; }
  __syncthreads();
  if (t == 0) {
    float S = rs[0] + rs[1] + rs[2] + rs[3];
    float Q = rq[0] + rq[1] + rq[2] + rq[3];
    const float inv = 1.f / (float)(NB * NN);
    float mu = S * inv;
    float var = fmaxf(Q * inv - mu * mu, 0.f);
    bn5[o] = mu;
    bn5[512 + o] = rsqrtf(var + EPSF);
  }
}

__global__ __launch_bounds__(256) void final_kernel(const float* __restrict__ y5,
    const float* __restrict__ bn5, const float* __restrict__ gamma,
    const float* __restrict__ beta, float* __restrict__ out)
{
  __shared__ float rm[4], rs[4];
  const int o = blockIdx.x, b = blockIdx.y, t = threadIdx.x, lane = t & 63, wave = t >> 6;
  const float mu = bn5[o], iv = bn5[512 + o], g = gamma[o], be = beta[o];
  const float* p = y5 + ((size_t)b * 512 + o) * NN;
  float mx = -3.4e38f, sm = 0.f;
  for (int n = t; n < NN; n += 256) {
    float z = (p[n] - mu) * iv;
    z = z * g + be;
    z = (z >= 0.f) ? z : 0.2f * z;
    mx = fmaxf(mx, z);
    sm += z;
  }
#pragma unroll
  for (int d = 1; d < 64; d <<= 1) { mx = fmaxf(mx, shflx_f(mx, d)); sm += shflx_f(sm, d); }
  if (lane == 0) { rm[wave] = mx; rs[wave] = sm; }
  __syncthreads();
  if (t == 0) {
    float M = fmaxf(fmaxf(rm[0], rm[1]), fmaxf(rm[2], rm[3]));
    float S = rs[0] + rs[1] + rs[2] + rs[3];
    out[(size_t)b * 1024 + o] = M;
    out[(size_t)b * 1024 + 512 + o] = S * (1.f / NN);
  }
}

extern "C" void kernel_launch(void* const* d_in, const int* in_sizes, int n_in,
                              void* d_out, int out_size, void* d_ws, size_t ws_size,
                              hipStream_t stream)
{
  (void)in_sizes; (void)n_in; (void)out_size; (void)ws_size;
  const float* x  = (const float*)d_in[0];
  const float* w1 = (const float*)d_in[1];
  const float* w2 = (const float*)d_in[2];
  const float* w3 = (const float*)d_in[3];
  const float* w4 = (const float*)d_in[4];
  const float* w5 = (const float*)d_in[5];
  const float* g5 = (const float*)d_in[6];
  const float* b5 = (const float*)d_in[7];
  float* out = (float*)d_out;

  // workspace layout (same 137 MB footprint)
  float* ws   = (float*)d_ws;
  float* xcat = ws;                         // 16*512*2048 fp32 (67.1 MB)
  float* Ub   = xcat + 16777216;            // 8.39M floats (33.5 MB)
  float* Vb   = Ub + 8388608;               // 8.39M floats (33.5 MB)
  int*   idxb = (int*)(Vb + 8388608);       // 16*2048*20 ints
  float* xxb  = (float*)(idxb + 655360);    // 32768 floats
  float* bn5  = xxb + 32768;                // 1024

  // Vb carve-up: xth | xtl | cntb (4-chunk counts) | weight stash
  _Float16* xth = (_Float16*)Vb;                       // 4.19M halves
  _Float16* xtl = xth + 4194304;                       // 4.19M halves
  int* cntb = (int*)(Vb + 4194304);                    // 131072 ints
  _Float16* wuh = (_Float16*)(Vb + 4325376);           // 4 x 32768 halves
  _Float16* wul = wuh + 32768;
  _Float16* wvh = wul + 32768;
  _Float16* wvl = wvh + 32768;

  ull* slist = (ull*)Ub;       // survivor lists chunks 0,1 (dead after merge)
  ull* sl2   = (ull*)xcat;     // chunks 2,3 live in xcat's dead tail (>= coff)
  float* Uc = Ub;              // chunk U (up to 128ch = 4.19M floats)
  float* Vc = Ub + 4194304;    // chunk V (up to 128ch)

  _Float16* w5h = (_Float16*)idxb;   // idx dead after last edge
  _Float16* w5l = w5h + 262144;
  _Float16* xcfh = (_Float16*)Ub;
  _Float16* xcfl = (_Float16*)Vb;
  float* y5 = xcat;

  struct Lyr { const float* xin; long bstride; int C, KB, O, coff; const float* w; };
  const Lyr L[4] = {
    { x,              3L * NN,   3,   1, 64,  0,   w1 },
    { xcat,           512L * NN, 64,  2, 64,  64,  w2 },
    { xcat + 64 * NN, 512L * NN, 64,  2, 128, 128, w3 },
    { xcat + 128 * NN,512L * NN, 128, 4, 256, 256, w4 },
  };

  for (int l = 0; l < 4; l++) {
    const int Cp = L[l].KB * 32, O = L[l].O, C = L[l].C, coff = L[l].coff;
    prep_kernel<<<dim3(NN / 256, NB), 256, 0, stream>>>(L[l].xin, xth, xtl, xxb,
                                                        C, L[l].KB, L[l].bstride);
    switch (L[l].KB) {
      case 1: knn4<1><<<dim3(NB * 4, 4), 512, 0, stream>>>(xth, xtl, xxb, slist, sl2, coff, cntb); break;
      case 2: knn4<2><<<dim3(NB * 4, 4), 512, 0, stream>>>(xth, xtl, xxb, slist, sl2, coff, cntb); break;
      default: knn4<4><<<dim3(NB * 4, 4), 512, 0, stream>>>(xth, xtl, xxb, slist, sl2, coff, cntb); break;
    }
    knn_merge4<<<dim3(NN / 4, NB), 256, 0, stream>>>(slist, sl2, coff, cntb,
                                                     xth, xtl, xxb, idxb, Cp, C);
    wcvt_uv<<<(O * Cp + 255) / 256, 256, 0, stream>>>(L[l].w, wuh, wul, wvh, wvl,
                                                      C, Cp, O);
    for (int c0 = 0; c0 < O; c0 += 128) {
      const int Och = (O - c0) < 128 ? (O - c0) : 128;
      uv_mfma<<<dim3(Och / 32, NN / 256, NB), 256, 0, stream>>>(
          wuh + (size_t)c0 * Cp, wul + (size_t)c0 * Cp,
          wvh + (size_t)c0 * Cp, wvl + (size_t)c0 * Cp,
          xth, xtl, Uc, Vc, Cp, Och);
      edge5<<<dim3(Och / 2, NB), 256, 0, stream>>>(Uc, Vc, idxb,
          xcat + (size_t)(L[l].coff + c0) * NN, Och);
    }
  }
  w5cvt<<<1024, 256, 0, stream>>>(w5, w5h, w5l);
  y5cvt_kernel<<<dim3(NN / 256, NB, 4), 256, 0, stream>>>(xcat, xcfh, xcfl);
  y5_mfma<<<dim3(2, NN / 128, NB), 256, 0, stream>>>(w5h, w5l, xcfh, xcfl, y5);
  bn5stat_kernel<<<512, 256, 0, stream>>>(y5, bn5);
  final_kernel<<<dim3(512, NB), 256, 0, stream>>>(y5, bn5, g5, b5, out);
}

// Round 13
// 1737.156 us; speedup vs baseline: 1.0939x; 1.0939x over previous
//
#include <hip/hip_runtime.h>

#define NN 2048      // points
#define NB 16        // batch
#define KK 20        // k neighbors
#define EPSF 1e-5f

typedef unsigned long long ull;
typedef _Float16 v8h __attribute__((ext_vector_type(8)));
typedef float v4f __attribute__((ext_vector_type(4)));

__device__ __forceinline__ float shflx_f(float v, int m) { return __shfl_xor(v, m, 64); }
__device__ __forceinline__ ull shflx_u64(ull v, int m) {
  int lo = __shfl_xor((int)(unsigned)v, m, 64);
  int hi = __shfl_xor((int)(unsigned)(v >> 32), m, 64);
  return (((ull)(unsigned)hi) << 32) | (unsigned)lo;
}
__device__ __forceinline__ ull packkey(float s, int n) {
  unsigned u = __float_as_uint(s);
  u = (u & 0x80000000u) ? ~u : (u | 0x80000000u);
  return (((ull)u) << 32) | (unsigned)(2047 - n);   // ties -> lowest index wins under max
}

// ---------------- prep: x[C][N] fp32 -> fragment-ready f16 hi/lo [n][Cp] + xx ----
__global__ __launch_bounds__(256) void prep_kernel(const float* __restrict__ x,
    _Float16* __restrict__ xh, _Float16* __restrict__ xl, float* __restrict__ xx,
    int C, int KB, long bstride)
{
  const int b = blockIdx.y;
  const int n = blockIdx.x * 256 + threadIdx.x;
  const float* xb = x + (size_t)b * bstride;
  const int Cp = KB * 32;
  _Float16* ph = xh + ((size_t)b * NN + n) * Cp;
  _Float16* pl = xl + ((size_t)b * NN + n) * Cp;
  float s = 0.f;
  for (int kb = 0; kb < KB; kb++) {
    for (int g = 0; g < 4; g++) {
      v8h hv, lv;
#pragma unroll
      for (int j = 0; j < 8; j++) {
        int c = kb * 32 + g * 8 + j;
        float v = (c < C) ? xb[(size_t)c * NN + n] : 0.f;
        _Float16 h = (_Float16)v;
        hv[j] = h;
        lv[j] = (_Float16)(v - (float)h);
        s = fmaf(v, v, s);
      }
      *(v8h*)(ph + kb * 32 + g * 8) = hv;
      *(v8h*)(pl + kb * 32 + g * 8) = lv;
    }
  }
  xx[b * NN + n] = s;
}

// ---------------- tile scorer: 64 queries (4 A-tiles) x 16 candidates ----------
template<int KB>
__device__ __forceinline__ void tile_scores(const v8h (&Bh)[KB], const v8h (&Bl)[KB],
    const v8h (&Ah)[4][KB], const v8h (&Al)[4][KB], float xv, v4f (&out)[4])
{
#pragma unroll
  for (int a = 0; a < 4; a++) {
    v4f a0 = {0.f, 0.f, 0.f, 0.f};
    v4f a1 = {0.f, 0.f, 0.f, 0.f};
#pragma unroll
    for (int kb = 0; kb < KB; kb++) {
      v4f& acc = (kb & 1) ? a1 : a0;
      acc = __builtin_amdgcn_mfma_f32_16x16x32_f16(Ah[a][kb], Bh[kb], acc, 0, 0, 0);
      acc = __builtin_amdgcn_mfma_f32_16x16x32_f16(Ah[a][kb], Bl[kb], acc, 0, 0, 0);
      acc = __builtin_amdgcn_mfma_f32_16x16x32_f16(Al[a][kb], Bh[kb], acc, 0, 0, 0);
    }
    v4f s = a0 + a1;
#pragma unroll
    for (int j = 0; j < 4; j++) out[a][j] = s[j] - 0.5f * xv;
  }
}

// ---------------- kNN stage 1: 64 q/wave, LDS-staged shared B tiles ------------
// Same math as the proven knn2 (bit-identical scores), but the 16-candidate
// tile is staged into LDS once per block (each wave stages 1/4) with a double
// buffer: global->reg issued at iteration start (latency hidden behind the
// 48-MFMA compute), ds_write + one barrier per tile. Cuts the 4x redundant
// per-wave global B-reads and fixes the per-wave load-latency stall.
template<int KB>
__global__ __launch_bounds__(256, 1) void knn5(
    const _Float16* __restrict__ xh, const _Float16* __restrict__ xl,
    const float* __restrict__ xxg, ull* __restrict__ slistG, int* __restrict__ cntG)
{
  constexpr int Cp = KB * 32;
  constexpr int RS = Cp + 8;            // padded row stride (halves) -> no bank hot-spots
  __shared__ float gmL[256][33];
  __shared__ float tauL[256];
  __shared__ int scnt[256];
  __shared__ _Float16 sBh[2][16 * RS];
  __shared__ _Float16 sBl[2][16 * RS];

  const int t = threadIdx.x;
  const int lane = t & 63;
  const int wave = t >> 6;
  const int col = lane & 15;
  const int quad = lane >> 4;
  const int quad8 = quad * 8;
  const int b = blockIdx.x >> 1;
  const int chunk = blockIdx.x & 1;
  const int qg = blockIdx.y;
  const int cb = chunk * 1024;
  const _Float16* xhb = xh + (size_t)b * NN * Cp;
  const _Float16* xlb = xl + (size_t)b * NN * Cp;
  const float* xxb = xxg + b * NN;

  v8h Ah[4][KB], Al[4][KB];
  const int qw = qg * 256 + wave * 64;
#pragma unroll
  for (int a = 0; a < 4; a++) {
    const _Float16* pa = xhb + (size_t)(qw + a * 16 + col) * Cp + quad8;
    const _Float16* pb = xlb + (size_t)(qw + a * 16 + col) * Cp + quad8;
#pragma unroll
    for (int kb = 0; kb < KB; kb++) {
      Ah[a][kb] = *(const v8h*)(pa + kb * 32);
      Al[a][kb] = *(const v8h*)(pb + kb * 32);
    }
  }

  // staging role: nl threads move 16*Cp halves (v8h each) per buffer half
  constexpr int NL = (16 * Cp) / 8;
  const int ci = t / (Cp / 8);
  const int c8 = (t % (Cp / 8)) * 8;
  v8h rH, rL;
  auto stageG = [&](int tt) {          // global -> regs (async w.r.t. compute)
    int t2 = tt < 63 ? tt : 63;
    if (t < NL) {
      size_t off = (size_t)(cb + t2 * 16 + ci) * Cp + c8;
      rH = *(const v8h*)(xhb + off);
      rL = *(const v8h*)(xlb + off);
    }
  };
  auto stageW = [&](int buf) {         // regs -> LDS
    if (t < NL) {
      *(v8h*)&sBh[buf][ci * RS + c8] = rH;
      *(v8h*)&sBl[buf][ci * RS + c8] = rL;
    }
  };

  // ---- pass 1: group maxima (16 cols x 2 tile-parities = 32 groups/query) ----
  float gm[4][8];
#pragma unroll
  for (int a = 0; a < 4; a++)
#pragma unroll
    for (int j = 0; j < 8; j++) gm[a][j] = -3.4e38f;

  stageG(0); stageW(0); __syncthreads();
  for (int tt = 0; tt < 64; tt++) {
    stageG(tt + 1);
    {
      const int buf = tt & 1;
      float xv = xxb[cb + tt * 16 + col];
      v8h Bh[KB], Bl[KB];
#pragma unroll
      for (int kb = 0; kb < KB; kb++) {
        Bh[kb] = *(const v8h*)&sBh[buf][col * RS + kb * 32 + quad8];
        Bl[kb] = *(const v8h*)&sBl[buf][col * RS + kb * 32 + quad8];
      }
      v4f out[4];
      tile_scores<KB>(Bh, Bl, Ah, Al, xv, out);
      const int par = tt & 1;
#pragma unroll
      for (int a = 0; a < 4; a++)
#pragma unroll
        for (int j = 0; j < 4; j++) gm[a][j * 2 + par] = fmaxf(gm[a][j * 2 + par], out[a][j]);
    }
    stageW((tt + 1) & 1);
    __syncthreads();
  }

#pragma unroll
  for (int a = 0; a < 4; a++)
#pragma unroll
    for (int j = 0; j < 4; j++) {
      int qi = wave * 64 + a * 16 + quad * 4 + j;
      gmL[qi][col * 2 + 0] = gm[a][j * 2 + 0];
      gmL[qi][col * 2 + 1] = gm[a][j * 2 + 1];
    }
  scnt[t] = 0;
  asm volatile("s_waitcnt lgkmcnt(0)" ::: "memory");

  // tau = rank-19 of 32 group maxima (provably <= true 20th score of the chunk)
  for (int r = 0; r < 32; r++) {
    const int q = wave * 64 + r * 2 + (lane >> 5);
    const int idx = lane & 31;
    float v = gmL[q][idx];
#pragma unroll
    for (int kk = 2; kk <= 32; kk <<= 1) {
#pragma unroll
      for (int m = kk >> 1; m >= 1; m >>= 1) {
        float o = shflx_f(v, m);
        bool keepmax = ((idx & kk) == 0) == ((idx & m) == 0);
        v = keepmax ? fmaxf(v, o) : fminf(v, o);
      }
    }
    if (idx == 19) tauL[q] = v;
  }
  asm volatile("s_waitcnt lgkmcnt(0)" ::: "memory");

  float tq[4][4];
#pragma unroll
  for (int a = 0; a < 4; a++)
#pragma unroll
    for (int j = 0; j < 4; j++) tq[a][j] = tauL[wave * 64 + a * 16 + quad * 4 + j];

  // ---- pass 2: bitwise-identical rescore, compact survivors >= tau ----
  ull* slB = slistG + (((size_t)b * NN + qg * 256) * 2 + chunk) * 64;
  stageG(0); stageW(0); __syncthreads();
  for (int tt = 0; tt < 64; tt++) {
    stageG(tt + 1);
    {
      const int buf = tt & 1;
      float xv = xxb[cb + tt * 16 + col];
      v8h Bh[KB], Bl[KB];
#pragma unroll
      for (int kb = 0; kb < KB; kb++) {
        Bh[kb] = *(const v8h*)&sBh[buf][col * RS + kb * 32 + quad8];
        Bl[kb] = *(const v8h*)&sBl[buf][col * RS + kb * 32 + quad8];
      }
      v4f out[4];
      tile_scores<KB>(Bh, Bl, Ah, Al, xv, out);
      int n = cb + tt * 16 + col;
#pragma unroll
      for (int a = 0; a < 4; a++)
#pragma unroll
        for (int j = 0; j < 4; j++) {
          float sc = out[a][j];
          if (sc >= tq[a][j]) {
            int qi = wave * 64 + a * 16 + quad * 4 + j;
            int pos = atomicAdd(&scnt[qi], 1);
            if (pos < 64) slB[(size_t)qi * 128 + pos] = packkey(sc, n);
          }
        }
    }
    stageW((tt + 1) & 1);
    __syncthreads();
  }
  asm volatile("s_waitcnt lgkmcnt(0)" ::: "memory");
  cntG[((size_t)b * NN + qg * 256 + t) * 2 + chunk] = scnt[t];
}

// ---------------- kNN stage 2: merge 2 chunk survivor lists -> top-20 --------
__global__ __launch_bounds__(256) void knn_merge(const ull* __restrict__ slistG,
    const int* __restrict__ cntG, const _Float16* __restrict__ xh,
    const _Float16* __restrict__ xl, const float* __restrict__ xxg,
    int* __restrict__ idxout, int Cp, int C)
{
  const int lane = threadIdx.x & 63, wave = threadIdx.x >> 6;
  const int b = blockIdx.y;
  const int q = blockIdx.x * 4 + wave;
  const int c0 = cntG[((size_t)b * NN + q) * 2 + 0];
  const int c1 = cntG[((size_t)b * NN + q) * 2 + 1];
  int* op = idxout + ((size_t)b * NN + q) * KK;

  if (c0 <= 64 && c1 <= 64) {
    const ull* s0 = slistG + ((size_t)b * NN + q) * 128;
    const int total = c0 + c1;
    ull e0 = 0, e1 = 0;
    int p0 = lane, p1 = lane + 64;
    if (p0 < total) e0 = (p0 < c0) ? s0[p0] : s0[64 + p0 - c0];
    if (p1 < total) e1 = (p1 < c0) ? s0[p1] : s0[64 + p1 - c0];
    for (int s = 0; s < KK; s++) {
      ull m = e0 > e1 ? e0 : e1;
      ull g = m;
#pragma unroll
      for (int d = 1; d < 64; d <<= 1) { ull o = shflx_u64(g, d); g = o > g ? o : g; }
      if (lane == 0) op[s] = 2047 - (int)(g & 0xFFFFFFFFu);
      if (e0 == g) e0 = 0; else if (e1 == g) e1 = 0;
    }
  } else {
    // exact fallback (survivor cap overflow — expected never): full fp32 rescan
    const _Float16* qh = xh + ((size_t)b * NN + q) * Cp;
    const _Float16* ql = xl + ((size_t)b * NN + q) * Cp;
    const float* xxb = xxg + b * NN;
    float sc[32];
#pragma unroll
    for (int i = 0; i < 32; i++) sc[i] = -0.5f * xxb[lane + 64 * i];
    for (int c = 0; c < C; c++) {
      float qv = (float)qh[c] + (float)ql[c];
      for (int i = 0; i < 32; i++) {
        int n = lane + 64 * i;
        float bv = (float)xh[((size_t)b * NN + n) * Cp + c] + (float)xl[((size_t)b * NN + n) * Cp + c];
        sc[i] = fmaf(qv, bv, sc[i]);
      }
    }
    for (int s = 0; s < KK; s++) {
      ull m = 0; int mi = -1;
      for (int i = 0; i < 32; i++) {
        ull k = packkey(sc[i], lane + 64 * i);
        if (k > m) { m = k; mi = i; }
      }
      ull g = m;
#pragma unroll
      for (int d = 1; d < 64; d <<= 1) { ull o = shflx_u64(g, d); g = o > g ? o : g; }
      if (lane == 0) op[s] = 2047 - (int)(g & 0xFFFFFFFFu);
      if (m == g && mi >= 0) sc[mi] = -3.4e38f;
    }
  }
}

// ---------------- weight converts ----------------
__global__ __launch_bounds__(256) void wcvt_uv(const float* __restrict__ w,
    _Float16* __restrict__ wuh, _Float16* __restrict__ wul,
    _Float16* __restrict__ wvh, _Float16* __restrict__ wvl, int C, int Cp, int O)
{
  int idx = blockIdx.x * 256 + threadIdx.x;
  if (idx >= O * Cp) return;
  int o = idx / Cp, c = idx - o * Cp;
  float a = 0.f, bv = 0.f;
  if (c < C) { a = w[o * 2 * C + c]; bv = w[o * 2 * C + C + c]; }
  float v = bv - a;
  _Float16 ah = (_Float16)a; wuh[idx] = ah; wul[idx] = (_Float16)(a - (float)ah);
  _Float16 vh = (_Float16)v; wvh[idx] = vh; wvl[idx] = (_Float16)(v - (float)vh);
}

__global__ __launch_bounds__(256) void w5cvt(const float* __restrict__ w5,
    _Float16* __restrict__ w5h, _Float16* __restrict__ w5l)
{
  int idx = blockIdx.x * 256 + threadIdx.x;
  float v = w5[idx];
  _Float16 h = (_Float16)v;
  w5h[idx] = h;
  w5l[idx] = (_Float16)(v - (float)h);
}

// ---------------- xcat fp32 [b][c][n] -> f16 hi/lo fragments [b][kc][n][32] ----
__global__ __launch_bounds__(256) void y5cvt_kernel(const float* __restrict__ xcat,
    _Float16* __restrict__ xh, _Float16* __restrict__ xl)
{
  const int b = blockIdx.y;
  const int n = blockIdx.x * 256 + threadIdx.x;
  for (int kc = blockIdx.z * 4; kc < blockIdx.z * 4 + 4; kc++) {
    v8h h[4], l[4];
#pragma unroll
    for (int g = 0; g < 4; g++)
#pragma unroll
      for (int j = 0; j < 8; j++) {
        float v = xcat[((size_t)b * 512 + kc * 32 + g * 8 + j) * NN + n];
        _Float16 hh = (_Float16)v;
        h[g][j] = hh;
        l[g][j] = (_Float16)(v - (float)hh);
      }
    size_t base = (((size_t)b * 16 + kc) * NN + n) * 32;
#pragma unroll
    for (int g = 0; g < 4; g++) {
      *(v8h*)(xh + base + g * 8) = h[g];
      *(v8h*)(xl + base + g * 8) = l[g];
    }
  }
}

// ---------------- y5 = w5 * xcat via MFMA (f16 hi/lo 3-product) ----------------
__global__ __launch_bounds__(256) void y5_mfma(const _Float16* __restrict__ w5h,
    const _Float16* __restrict__ w5l, const _Float16* __restrict__ xh,
    const _Float16* __restrict__ xl, float* __restrict__ y5)
{
  const int lane = threadIdx.x & 63, wave = threadIdx.x >> 6;
  const int col = lane & 15, quad = lane >> 4, quad8 = quad * 8;
  const int b = blockIdx.z;
  const int o0 = blockIdx.x * 256 + wave * 64;
  const int nb0 = blockIdx.y * 128;
  v4f acc[4][8];
#pragma unroll
  for (int a = 0; a < 4; a++)
#pragma unroll
    for (int t = 0; t < 8; t++) acc[a][t] = {0.f, 0.f, 0.f, 0.f};

  for (int kc = 0; kc < 16; kc++) {
    v8h Ah[4], Al[4];
#pragma unroll
    for (int a = 0; a < 4; a++) {
      size_t off = (size_t)(o0 + a * 16 + col) * 512 + kc * 32 + quad8;
      Ah[a] = *(const v8h*)(w5h + off);
      Al[a] = *(const v8h*)(w5l + off);
    }
#pragma unroll
    for (int t = 0; t < 8; t++) {
      int n = nb0 + t * 16 + col;
      size_t boff = (((size_t)b * 16 + kc) * NN + n) * 32 + quad8;
      v8h Bh = *(const v8h*)(xh + boff);
      v8h Bl = *(const v8h*)(xl + boff);
#pragma unroll
      for (int a = 0; a < 4; a++) {
        acc[a][t] = __builtin_amdgcn_mfma_f32_16x16x32_f16(Ah[a], Bh, acc[a][t], 0, 0, 0);
        acc[a][t] = __builtin_amdgcn_mfma_f32_16x16x32_f16(Ah[a], Bl, acc[a][t], 0, 0, 0);
        acc[a][t] = __builtin_amdgcn_mfma_f32_16x16x32_f16(Al[a], Bh, acc[a][t], 0, 0, 0);
      }
    }
  }
#pragma unroll
  for (int a = 0; a < 4; a++)
#pragma unroll
    for (int t = 0; t < 8; t++)
#pragma unroll
      for (int j = 0; j < 4; j++)
        y5[((size_t)b * 512 + o0 + a * 16 + quad * 4 + j) * NN + nb0 + t * 16 + col] = acc[a][t][j];
}

// ---------------- U/V chunk (up to 128 out-ch) via MFMA, 4 n-tiles/wave --------
__global__ __launch_bounds__(256) void uv_mfma(const _Float16* __restrict__ wuh,
    const _Float16* __restrict__ wul, const _Float16* __restrict__ wvh,
    const _Float16* __restrict__ wvl, const _Float16* __restrict__ xh,
    const _Float16* __restrict__ xl, float* __restrict__ Uc, float* __restrict__ Vc,
    int Cp, int Och)
{
  const int lane = threadIdx.x & 63, wave = threadIdx.x >> 6;
  const int col = lane & 15, quad = lane >> 4, quad8 = quad * 8;
  const int b = blockIdx.z;
  const int o0 = blockIdx.x * 32;           // chunk-local out channel base
  const int nb0 = blockIdx.y * 256 + wave * 64;
  v4f aU[2][4], aV[2][4];
#pragma unroll
  for (int a = 0; a < 2; a++)
#pragma unroll
    for (int t = 0; t < 4; t++) { aU[a][t] = {0.f,0.f,0.f,0.f}; aV[a][t] = {0.f,0.f,0.f,0.f}; }

  const int KBr = Cp >> 5;
  for (int kb = 0; kb < KBr; kb++) {
    v8h Uh[2], Ul[2], Vh[2], Vl[2];
#pragma unroll
    for (int a = 0; a < 2; a++) {
      size_t off = (size_t)(o0 + a * 16 + col) * Cp + kb * 32 + quad8;
      Uh[a] = *(const v8h*)(wuh + off);
      Ul[a] = *(const v8h*)(wul + off);
      Vh[a] = *(const v8h*)(wvh + off);
      Vl[a] = *(const v8h*)(wvl + off);
    }
#pragma unroll
    for (int t = 0; t < 4; t++) {
      int n = nb0 + t * 16 + col;
      size_t boff = ((size_t)b * NN + n) * Cp + kb * 32 + quad8;
      v8h Bh = *(const v8h*)(xh + boff);
      v8h Bl = *(const v8h*)(xl + boff);
#pragma unroll
      for (int a = 0; a < 2; a++) {
        aU[a][t] = __builtin_amdgcn_mfma_f32_16x16x32_f16(Uh[a], Bh, aU[a][t], 0, 0, 0);
        aU[a][t] = __builtin_amdgcn_mfma_f32_16x16x32_f16(Uh[a], Bl, aU[a][t], 0, 0, 0);
        aU[a][t] = __builtin_amdgcn_mfma_f32_16x16x32_f16(Ul[a], Bh, aU[a][t], 0, 0, 0);
        aV[a][t] = __builtin_amdgcn_mfma_f32_16x16x32_f16(Vh[a], Bh, aV[a][t], 0, 0, 0);
        aV[a][t] = __builtin_amdgcn_mfma_f32_16x16x32_f16(Vh[a], Bl, aV[a][t], 0, 0, 0);
        aV[a][t] = __builtin_amdgcn_mfma_f32_16x16x32_f16(Vl[a], Bh, aV[a][t], 0, 0, 0);
      }
    }
  }
#pragma unroll
  for (int a = 0; a < 2; a++)
#pragma unroll
    for (int t = 0; t < 4; t++)
#pragma unroll
      for (int j = 0; j < 4; j++) {
        size_t base = ((size_t)b * Och + o0 + a * 16 + quad * 4 + j) * NN + nb0 + t * 16 + col;
        Uc[base] = aU[a][t][j];
        Vc[base] = aV[a][t][j];
      }
}

// ---------------- edge5: 2 channels/block, 2-pass, 2-4 blocks/CU ---------------
__global__ __launch_bounds__(256) void edge5(const float* __restrict__ Uc,
    const float* __restrict__ Vc, const int* __restrict__ idx,
    float* __restrict__ xo, int Och)
{
  __shared__ float Ur[2 * 2052];   // +4 pad breaks power-of-2 collisions
  __shared__ float red[4][4];
  __shared__ float smv[4];
  const int b = blockIdx.y, o0 = blockIdx.x * 2;
  const int t = threadIdx.x, lane = t & 63, wave = t >> 6;
  for (int r = 0; r < 2; r++)
    for (int i = t; i < NN; i += 256)
      Ur[r * 2052 + i] = Uc[((size_t)b * Och + o0 + r) * NN + i];
  __syncthreads();
  const float* Vp = Vc + ((size_t)b * Och + o0) * NN;
  const int* ib = idx + (size_t)b * NN * KK;
  float s0 = 0, s1 = 0, c0 = 0, c1 = 0;
  for (int n = t; n < NN; n += 256) {
    float v0 = Vp[n], v1 = Vp[NN + n];
    const int* ip = ib + (size_t)n * KK;
#pragma unroll
    for (int j = 0; j < KK; j++) {
      int m = ip[j];
      float y0 = Ur[m] + v0, y1 = Ur[2052 + m] + v1;
      s0 += y0; c0 = fmaf(y0, y0, c0);
      s1 += y1; c1 = fmaf(y1, y1, c1);
    }
  }
  float st[4] = { s0, s1, c0, c1 };
#pragma unroll
  for (int k = 0; k < 4; k++) {
    float a = st[k];
#pragma unroll
    for (int d = 1; d < 64; d <<= 1) a += shflx_f(a, d);
    if (lane == 0) red[k][wave] = a;
  }
  __syncthreads();
  if (t < 2) {
    float a = red[t][0] + red[t][1] + red[t][2] + red[t][3];
    float c = red[2 + t][0] + red[2 + t][1] + red[2 + t][2] + red[2 + t][3];
    const float inv = 1.f / (float)(NN * KK);
    float mu = a * inv;
    float var = fmaxf(c * inv - mu * mu, 0.f);
    smv[t] = mu;
    smv[2 + t] = rsqrtf(var + EPSF);
  }
  __syncthreads();
  const float mu0 = smv[0], mu1 = smv[1], i0 = smv[2], i1 = smv[3];
  for (int n = t; n < NN; n += 256) {
    float v0 = Vp[n], v1 = Vp[NN + n];
    const int* ip = ib + (size_t)n * KK;
    float m0 = -3.4e38f, m1 = m0;
#pragma unroll
    for (int j = 0; j < KK; j++) {
      int m = ip[j];
      m0 = fmaxf(m0, Ur[m] + v0);
      m1 = fmaxf(m1, Ur[2052 + m] + v1);
    }
    float z;  // leaky-relu commutes with max (i > 0)
    z = (m0 - mu0) * i0; xo[((size_t)b * 512 + o0 + 0) * NN + n] = z >= 0.f ? z : 0.2f * z;
    z = (m1 - mu1) * i1; xo[((size_t)b * 512 + o0 + 1) * NN + n] = z >= 0.f ? z : 0.2f * z;
  }
}

__global__ __launch_bounds__(256) void bn5stat_kernel(const float* __restrict__ y5,
    float* __restrict__ bn5) {
  __shared__ float rs[4], rq[4];
  const int o = blockIdx.x, t = threadIdx.x, lane = t & 63, wave = t >> 6;
  float s = 0.f, q = 0.f;
  for (int b = 0; b < NB; b++) {
    const float* p = y5 + ((size_t)b * 512 + o) * NN;
    for (int n = t; n < NN; n += 256) { float v = p[n]; s += v; q = fmaf(v, v, q); }
  }
#pragma unroll
  for (int d = 1; d < 64; d <<= 1) { s += shflx_f(s, d); q += shflx_f(q, d); }
  if (lane == 0) { rs[wave] = s; rq[wave] = q; }
  __syncthreads();
  if (t == 0) {
    float S = rs[0] + rs[1] + rs[2] + rs[3];
    float Q = rq[0] + rq[1] + rq[2] + rq[3];
    const float inv = 1.f / (float)(NB * NN);
    float mu = S * inv;
    float var = fmaxf(Q * inv - mu * mu, 0.f);
    bn5[o] = mu;
    bn5[512 + o] = rsqrtf(var + EPSF);
  }
}

__global__ __launch_bounds__(256) void final_kernel(const float* __restrict__ y5,
    const float* __restrict__ bn5, const float* __restrict__ gamma,
    const float* __restrict__ beta, float* __restrict__ out)
{
  __shared__ float rm[4], rs[4];
  const int o = blockIdx.x, b = blockIdx.y, t = threadIdx.x, lane = t & 63, wave = t >> 6;
  const float mu = bn5[o], iv = bn5[512 + o], g = gamma[o], be = beta[o];
  const float* p = y5 + ((size_t)b * 512 + o) * NN;
  float mx = -3.4e38f, sm = 0.f;
  for (int n = t; n < NN; n += 256) {
    float z = (p[n] - mu) * iv;
    z = z * g + be;
    z = (z >= 0.f) ? z : 0.2f * z;
    mx = fmaxf(mx, z);
    sm += z;
  }
#pragma unroll
  for (int d = 1; d < 64; d <<= 1) { mx = fmaxf(mx, shflx_f(mx, d)); sm += shflx_f(sm, d); }
  if (lane == 0) { rm[wave] = mx; rs[wave] = sm; }
  __syncthreads();
  if (t == 0) {
    float M = fmaxf(fmaxf(rm[0], rm[1]), fmaxf(rm[2], rm[3]));
    float S = rs[0] + rs[1] + rs[2] + rs[3];
    out[(size_t)b * 1024 + o] = M;
    out[(size_t)b * 1024 + 512 + o] = S * (1.f / NN);
  }
}

extern "C" void kernel_launch(void* const* d_in, const int* in_sizes, int n_in,
                              void* d_out, int out_size, void* d_ws, size_t ws_size,
                              hipStream_t stream)
{
  (void)in_sizes; (void)n_in; (void)out_size; (void)ws_size;
  const float* x  = (const float*)d_in[0];
  const float* w1 = (const float*)d_in[1];
  const float* w2 = (const float*)d_in[2];
  const float* w3 = (const float*)d_in[3];
  const float* w4 = (const float*)d_in[4];
  const float* w5 = (const float*)d_in[5];
  const float* g5 = (const float*)d_in[6];
  const float* b5 = (const float*)d_in[7];
  float* out = (float*)d_out;

  // workspace layout (same 137 MB footprint)
  float* ws   = (float*)d_ws;
  float* xcat = ws;                         // 16*512*2048 fp32 (67.1 MB)
  float* Ub   = xcat + 16777216;            // 8.39M floats (33.5 MB)
  float* Vb   = Ub + 8388608;               // 8.39M floats (33.5 MB)
  int*   idxb = (int*)(Vb + 8388608);       // 16*2048*20 ints
  float* xxb  = (float*)(idxb + 655360);    // 32768 floats
  float* bn5  = xxb + 32768;                // 1024

  // Vb carve-up: xth | xtl | cntb | weight stash
  _Float16* xth = (_Float16*)Vb;                       // 4.19M halves
  _Float16* xtl = xth + 4194304;                       // 4.19M halves
  int* cntb = (int*)(Vb + 4194304);                    // 65536 ints
  _Float16* wuh = (_Float16*)(Vb + 4259840);           // 4 x 32768 halves
  _Float16* wul = wuh + 32768;
  _Float16* wvh = wul + 32768;
  _Float16* wvl = wvh + 32768;

  ull* slist = (ull*)Ub;       // survivor lists alias Ub (dead after merge)
  float* Uc = Ub;              // chunk U (up to 128ch = 4.19M floats)
  float* Vc = Ub + 4194304;    // chunk V (up to 128ch)

  _Float16* w5h = (_Float16*)idxb;   // idx dead after last edge
  _Float16* w5l = w5h + 262144;
  _Float16* xcfh = (_Float16*)Ub;
  _Float16* xcfl = (_Float16*)Vb;
  float* y5 = xcat;

  struct Lyr { const float* xin; long bstride; int C, KB, O, coff; const float* w; };
  const Lyr L[4] = {
    { x,              3L * NN,   3,   1, 64,  0,   w1 },
    { xcat,           512L * NN, 64,  2, 64,  64,  w2 },
    { xcat + 64 * NN, 512L * NN, 64,  2, 128, 128, w3 },
    { xcat + 128 * NN,512L * NN, 128, 4, 256, 256, w4 },
  };

  for (int l = 0; l < 4; l++) {
    const int Cp = L[l].KB * 32, O = L[l].O, C = L[l].C;
    prep_kernel<<<dim3(NN / 256, NB), 256, 0, stream>>>(L[l].xin, xth, xtl, xxb,
                                                        C, L[l].KB, L[l].bstride);
    switch (L[l].KB) {
      case 1: knn5<1><<<dim3(NB * 2, NN / 256), 256, 0, stream>>>(xth, xtl, xxb, slist, cntb); break;
      case 2: knn5<2><<<dim3(NB * 2, NN / 256), 256, 0, stream>>>(xth, xtl, xxb, slist, cntb); break;
      default: knn5<4><<<dim3(NB * 2, NN / 256), 256, 0, stream>>>(xth, xtl, xxb, slist, cntb); break;
    }
    knn_merge<<<dim3(NN / 4, NB), 256, 0, stream>>>(slist, cntb, xth, xtl, xxb, idxb,
                                                    Cp, C);
    wcvt_uv<<<(O * Cp + 255) / 256, 256, 0, stream>>>(L[l].w, wuh, wul, wvh, wvl,
                                                      C, Cp, O);
    for (int c0 = 0; c0 < O; c0 += 128) {
      const int Och = (O - c0) < 128 ? (O - c0) : 128;
      uv_mfma<<<dim3(Och / 32, NN / 256, NB), 256, 0, stream>>>(
          wuh + (size_t)c0 * Cp, wul + (size_t)c0 * Cp,
          wvh + (size_t)c0 * Cp, wvl + (size_t)c0 * Cp,
          xth, xtl, Uc, Vc, Cp, Och);
      edge5<<<dim3(Och / 2, NB), 256, 0, stream>>>(Uc, Vc, idxb,
          xcat + (size_t)(L[l].coff + c0) * NN, Och);
    }
  }
  w5cvt<<<1024, 256, 0, stream>>>(w5, w5h, w5l);
  y5cvt_kernel<<<dim3(NN / 256, NB, 4), 256, 0, stream>>>(xcat, xcfh, xcfl);
  y5_mfma<<<dim3(2, NN / 128, NB), 256, 0, stream>>>(w5h, w5l, xcfh, xcfl, y5);
  bn5stat_kernel<<<512, 256, 0, stream>>>(y5, bn5);
  final_kernel<<<dim3(512, NB), 256, 0, stream>>>(y5, bn5, g5, b5, out);
}